// Round 11
// baseline (364.677 us; speedup 1.0000x reference)
//
#include <hip/hip_runtime.h>
#include <math.h>

// Problem: B=128, P=128, D=128, N=4096, fp32 in/out.
// probs = softmax(10*tanh((A@K)/sqrt(128)) + mask) over n.
//
// R10 pivot: fp16x3-split MFMA GEMM (matrix pipe) + two-pass softmax.
//  K1: score logits z = 10*tanh((A@K)/sqrt(128)) + mask -> O   (no LDS/barriers)
//  K2: row softmax over O in-place (one wave per row, row fits in 64 VGPRs)
constexpr int BB = 128;
constexpr int PP = 128;
constexpr int DD = 128;
constexpr int NN = 4096;
constexpr float kC = 10.0f;
constexpr float k2InvSqrtD = 0.1767766952966369f;   // 2/sqrt(128)

typedef float f32x4 __attribute__((ext_vector_type(4)));
typedef _Float16 f16x8 __attribute__((ext_vector_type(8)));

// clipped = 10*tanh(s/sqrt(128)) + m, via tanh(x) = 1 - 2/(e^{2x}+1)
__device__ __forceinline__ float clip1(float s, float m) {
    const float e2 = __expf(s * k2InvSqrtD);
    const float r = __builtin_amdgcn_rcpf(e2 + 1.0f);
    return fmaf(-2.0f * kC, r, kC) + m;
}

// ============================ Kernel 1: GEMM + clip ============================
// Grid: 4096 blocks = 128 b x 8 ptile x 4 nstrip. 512 thr = 8 waves; each wave
// owns a 16-row x 128-col subtile of its block's 16 x 1024 output strip.
// fp16x3 split: a = hi + lo exactly to ~2^-22 rel; score = hi*hi + hi*lo + lo*hi.
// Operand k-packing below is assumed (k = 4g + (j&3) + 16(j>>2), g=lane>>4) but
// applied IDENTICALLY to A and B fragments, so any mis-guess is a k-permutation
// that cancels in the MFMA dot product. C/D layout is the HW-verified one:
// col = lane&15, row = 4*(lane>>4) + reg.
__global__ __launch_bounds__(512, 2)
void score_kernel(const float* __restrict__ A,   // [B][P][D]
                  const float* __restrict__ K,   // [B][D][N]
                  const float* __restrict__ M,   // [B][P][N]
                  float* __restrict__ O) {       // [B][P][N] <- logits z
    // XCD swizzle: the 8 ptile-blocks sharing (b, nstrip) land on one XCD in
    // consecutive dispatch rounds -> K strip (512 KB) stays in that XCD's L2.
    const int l = blockIdx.x;
    const int xcd = l & 7;
    const int r = l >> 3;                  // 0..511 per XCD
    const int c = xcd + 8 * (r >> 3);      // combo id in [0,512)
    const int ptile = r & 7;
    const int b = c >> 2;                  // [0,128)
    const int ns = c & 3;                  // [0,4)
    const int p_base = ptile * 16;

    const int tid = (int)threadIdx.x;
    const int lane = tid & 63;
    const int wid = tid >> 6;
    const int col = lane & 15;             // A row / B col / C col
    const int g = lane >> 4;               // k-group (and C row group)
    const int kbase = 4 * g;

    // ---- A fragments (held in regs for the whole kernel): 16 rows x 128 d ----
    const float* Arow = A + (size_t)(b * PP + p_base + col) * DD;
    f16x8 ah[4], al[4];
    #pragma unroll
    for (int kb = 0; kb < 4; ++kb) {
        #pragma unroll
        for (int j = 0; j < 8; ++j) {
            const int d = kb * 32 + kbase + (j & 3) + 16 * (j >> 2);
            const float x = Arow[d];
            const _Float16 h = (_Float16)x;
            ah[kb][j] = h;
            al[kb][j] = (_Float16)(x - (float)h);
        }
    }

    const int n0 = ns * 1024 + wid * 128;
    const float* Kb = K + (size_t)b * DD * NN;

    #pragma unroll 2
    for (int nt = 0; nt < 8; ++nt) {
        const int n = n0 + nt * 16 + col;
        const float* Kcol = Kb + n;

        f32x4 acc = {0.f, 0.f, 0.f, 0.f};
        #pragma unroll
        for (int kb = 0; kb < 4; ++kb) {
            float kv[8];
            #pragma unroll
            for (int j = 0; j < 8; ++j) {
                const int d = kb * 32 + kbase + (j & 3) + 16 * (j >> 2);
                kv[j] = Kcol[(size_t)d * NN];
            }
            f16x8 bh, bl;
            #pragma unroll
            for (int j = 0; j < 8; ++j) {
                const _Float16 h = (_Float16)kv[j];
                bh[j] = h;
                bl[j] = (_Float16)(kv[j] - (float)h);
            }
            acc = __builtin_amdgcn_mfma_f32_16x16x32_f16(ah[kb], bh, acc, 0, 0, 0);
            acc = __builtin_amdgcn_mfma_f32_16x16x32_f16(ah[kb], bl, acc, 0, 0, 0);
            acc = __builtin_amdgcn_mfma_f32_16x16x32_f16(al[kb], bh, acc, 0, 0, 0);
        }

        // epilogue: z = 10*tanh(score/sqrt(128)) + mask -> O (raw logits)
        #pragma unroll
        for (int j = 0; j < 4; ++j) {
            const int row = p_base + kbase + j;   // C/D row = 4*(lane>>4)+j
            const size_t off = (size_t)(b * PP + row) * NN + n;
            O[off] = clip1(acc[j], M[off]);
        }
    }
}

// ============================ Kernel 2: row softmax ============================
// One wave per row; the full row (4096 f32 = 64/lane) lives in registers.
// In-place on O. 256 thr = 4 rows/block; grid = 16384/4 = 4096.
__global__ __launch_bounds__(256, 2)
void softmax_kernel(float* __restrict__ O) {
    const int row = blockIdx.x * 4 + ((int)threadIdx.x >> 6);
    const int lane = (int)threadIdx.x & 63;
    float4* R = (float4*)(O + (size_t)row * NN);

    float4 v[16];
    #pragma unroll
    for (int i = 0; i < 16; ++i) v[i] = R[i * 64 + lane];

    // row max
    float mx = fmaxf(fmaxf(v[0].x, v[0].y), fmaxf(v[0].z, v[0].w));
    #pragma unroll
    for (int i = 1; i < 16; ++i)
        mx = fmaxf(mx, fmaxf(fmaxf(v[i].x, v[i].y), fmaxf(v[i].z, v[i].w)));
    #pragma unroll
    for (int off = 32; off > 0; off >>= 1)
        mx = fmaxf(mx, __shfl_xor(mx, off));

    // exp + row sum
    float s = 0.f;
    #pragma unroll
    for (int i = 0; i < 16; ++i) {
        v[i].x = __expf(v[i].x - mx);
        v[i].y = __expf(v[i].y - mx);
        v[i].z = __expf(v[i].z - mx);
        v[i].w = __expf(v[i].w - mx);
        s += (v[i].x + v[i].y) + (v[i].z + v[i].w);
    }
    #pragma unroll
    for (int off = 32; off > 0; off >>= 1)
        s += __shfl_xor(s, off);

    const float inv = __builtin_amdgcn_rcpf(s);
    #pragma unroll
    for (int i = 0; i < 16; ++i) {
        v[i].x *= inv; v[i].y *= inv; v[i].z *= inv; v[i].w *= inv;
        R[i * 64 + lane] = v[i];
    }
}

extern "C" void kernel_launch(void* const* d_in, const int* in_sizes, int n_in,
                              void* d_out, int out_size, void* d_ws, size_t ws_size,
                              hipStream_t stream) {
    const float* A = (const float*)d_in[0];   // mh_attn_out [128][128][128]
    const float* K = (const float*)d_in[1];   // single_head_key [128][128][4096]
    const float* M = (const float*)d_in[2];   // mask [128][128][4096]
    float* O = (float*)d_out;                 // probs [128][128][4096]

    score_kernel<<<dim3(BB * 8 * 4), dim3(512), 0, stream>>>(A, K, M, O);
    softmax_kernel<<<dim3(BB * PP / 4), dim3(256), 0, stream>>>(O);
}

// Round 12
// 352.886 us; speedup vs baseline: 1.0334x; 1.0334x over previous
//
#include <hip/hip_runtime.h>
#include <math.h>

// Problem: B=128, P=128, D=128, N=4096, fp32 in/out.
// probs = softmax(10*tanh((A@K)/sqrt(128)) + mask) over n.
//
// R12: fp16x3 MFMA GEMM, 32 p-rows/wave (2 row-groups), max-free softmax:
//  K1: e = exp(10*tanh((A@K)/sqrt(128)) + mask) -> O; partial row sums -> ws
//      (valid because |10*tanh| <= 10 -> exp <= 2.2e4, sum <= 9e7: no overflow)
//  K2: O *= 1/rowsum  (pure streaming scale)
constexpr int BB = 128;
constexpr int PP = 128;
constexpr int DD = 128;
constexpr int NN = 4096;
constexpr float kC = 10.0f;
constexpr float k2InvSqrtD = 0.1767766952966369f;   // 2/sqrt(128)

typedef float f32x4 __attribute__((ext_vector_type(4)));
typedef _Float16 f16x8 __attribute__((ext_vector_type(8)));

__device__ __forceinline__ float4 ld_nt_f4(const float* p) {
    f32x4 v = __builtin_nontemporal_load((const f32x4*)p);
    return make_float4(v.x, v.y, v.z, v.w);
}
__device__ __forceinline__ float ld_nt_f(const float* p) {
    return __builtin_nontemporal_load(p);
}
__device__ __forceinline__ void st_nt_f4(float* p, float4 s) {
    f32x4 v = {s.x, s.y, s.z, s.w};
    __builtin_nontemporal_store(v, (f32x4*)p);
}

// z = 10*tanh(s/sqrt(128)) + m, via tanh(x) = 1 - 2/(e^{2x}+1)
__device__ __forceinline__ float clip1(float s, float m) {
    const float e2 = __expf(s * k2InvSqrtD);
    const float r = __builtin_amdgcn_rcpf(e2 + 1.0f);
    return fmaf(-2.0f * kC, r, kC) + m;
}

// ======================= Kernel 1: GEMM + clip + exp =========================
// Grid: 2048 = 128 b x 4 ptile(32 rows) x 4 nstrip(1024). 512 thr = 8 waves;
// wave owns 32 rows x 128 cols (8 nt tiles). fp16x3: score = hi*hi+hi*lo+lo*hi
// (k-packing applied identically to A and B -> any k-permutation cancels).
// C/D layout (HW-verified): col = lane&15, row = 4*(lane>>4) + reg.
__global__ __launch_bounds__(512, 2)
void score_kernel(const float* __restrict__ A,   // [B][P][D]
                  const float* __restrict__ K,   // [B][D][N]
                  const float* __restrict__ M,   // [B][P][N]
                  float* __restrict__ O,         // [B][P][N] <- exp(z)
                  float* __restrict__ ws) {      // [B*P][4] partial row sums
    __shared__ float rs[32][8];            // per-wave row partial sums

    // XCD swizzle: the 4 ptile blocks of one (b,ns) land on one XCD, l spaced
    // by 8 -> dispatched near-simultaneously; K strip (512 KB) L2-resident.
    const int l = blockIdx.x;
    const int xcd = l & 7;
    const int r = l >> 3;                  // 0..255
    const int c = xcd + 8 * (r >> 2);      // (b,ns) combo in [0,512)
    const int ptile = r & 3;
    const int b = c >> 2;
    const int ns = c & 3;
    const int p_base = ptile * 32;

    const int tid = (int)threadIdx.x;
    const int lane = tid & 63;
    const int wid = tid >> 6;
    const int col = lane & 15;             // A row-in-tile / B col / C col
    const int g = lane >> 4;               // k-group (and C row group)
    const int kbase = 4 * g;

    // ---- A fragments held for the whole kernel: 2 row-groups x 128 d ----
    f16x8 ah[2][4], al[2][4];
    #pragma unroll
    for (int rg = 0; rg < 2; ++rg) {
        const float* Arow = A + (size_t)(b * PP + p_base + rg * 16 + col) * DD;
        #pragma unroll
        for (int kb = 0; kb < 4; ++kb) {
            #pragma unroll
            for (int j = 0; j < 8; ++j) {
                const int d = kb * 32 + kbase + (j & 3) + 16 * (j >> 2);
                const float x = Arow[d];
                const _Float16 h = (_Float16)x;
                ah[rg][kb][j] = h;
                al[rg][kb][j] = (_Float16)(x - (float)h);
            }
        }
    }

    const int n0 = ns * 1024 + wid * 128;
    const float* Kb = K + (size_t)b * DD * NN;

    float rsum[8];                          // per-lane exp-sums, rows fixed/nt
    #pragma unroll
    for (int q = 0; q < 8; ++q) rsum[q] = 0.f;

    #pragma unroll 2
    for (int nt = 0; nt < 8; ++nt) {
        const int n = n0 + nt * 16 + col;
        const float* Kcol = Kb + n;

        // prefetch mask early (used only in epilogue)
        float mv[8];
        #pragma unroll
        for (int rg = 0; rg < 2; ++rg)
            #pragma unroll
            for (int j = 0; j < 4; ++j)
                mv[rg * 4 + j] = ld_nt_f(
                    &M[(size_t)(b * PP + p_base + rg * 16 + kbase + j) * NN + n]);

        f32x4 acc[2] = {{0.f, 0.f, 0.f, 0.f}, {0.f, 0.f, 0.f, 0.f}};
        #pragma unroll
        for (int kb = 0; kb < 4; ++kb) {
            float kv[8];
            #pragma unroll
            for (int j = 0; j < 8; ++j) {
                const int d = kb * 32 + kbase + (j & 3) + 16 * (j >> 2);
                kv[j] = Kcol[(size_t)d * NN];
            }
            f16x8 bh, bl;
            #pragma unroll
            for (int j = 0; j < 8; ++j) {
                const _Float16 h = (_Float16)kv[j];
                bh[j] = h;
                bl[j] = (_Float16)(kv[j] - (float)h);
            }
            #pragma unroll
            for (int rg = 0; rg < 2; ++rg) {
                acc[rg] = __builtin_amdgcn_mfma_f32_16x16x32_f16(ah[rg][kb], bh, acc[rg], 0, 0, 0);
                acc[rg] = __builtin_amdgcn_mfma_f32_16x16x32_f16(ah[rg][kb], bl, acc[rg], 0, 0, 0);
                acc[rg] = __builtin_amdgcn_mfma_f32_16x16x32_f16(al[rg][kb], bh, acc[rg], 0, 0, 0);
            }
        }

        // epilogue: e = exp(clip+mask); store e; accumulate row partials
        #pragma unroll
        for (int rg = 0; rg < 2; ++rg) {
            #pragma unroll
            for (int j = 0; j < 4; ++j) {
                const int row = p_base + rg * 16 + kbase + j;
                const size_t off = (size_t)(b * PP + row) * NN + n;
                const float e = __expf(clip1(acc[rg][j], mv[rg * 4 + j]));
                O[off] = e;                 // cacheable: K2 re-reads via L2/L3
                rsum[rg * 4 + j] += e;
            }
        }
    }

    // ---- reduce row partials: 16 cols (shfl) -> 8 waves (LDS) -> ws ----
    #pragma unroll
    for (int q = 0; q < 8; ++q) {
        float s = rsum[q];
        s += __shfl_xor(s, 1);
        s += __shfl_xor(s, 2);
        s += __shfl_xor(s, 4);
        s += __shfl_xor(s, 8);
        rsum[q] = s;
    }
    if (col == 0) {                        // lanes g*16, g = 0..3
        #pragma unroll
        for (int rg = 0; rg < 2; ++rg)
            #pragma unroll
            for (int j = 0; j < 4; ++j)
                rs[rg * 16 + kbase + j][wid] = rsum[rg * 4 + j];
    }
    __syncthreads();
    if (tid < 32) {
        float s = 0.f;
        #pragma unroll
        for (int w = 0; w < 8; ++w) s += rs[tid][w];
        ws[(size_t)(b * PP + p_base + tid) * 4 + ns] = s;
    }
}

// ========================= Kernel 2: scale by 1/rowsum ========================
// Pure streaming: 2048 blocks x 256 thr; 32 f4/thread, coalesced within row.
__global__ __launch_bounds__(256, 4)
void scale_kernel(float* __restrict__ O, const float* __restrict__ ws) {
    const int gtid = blockIdx.x * 256 + (int)threadIdx.x;
    const int row = gtid >> 5;             // 32 threads per row
    const int seg = gtid & 31;
    const float* w = ws + (size_t)row * 4;
    const float inv = __builtin_amdgcn_rcpf((w[0] + w[1]) + (w[2] + w[3]));

    float4* R = (float4*)(O + (size_t)row * NN);
    #pragma unroll 8
    for (int i = 0; i < 32; ++i) {
        const int idx = i * 32 + seg;      // lanes consecutive -> coalesced
        float4 v = R[idx];
        v.x *= inv; v.y *= inv; v.z *= inv; v.w *= inv;
        st_nt_f4((float*)&R[idx], v);
    }
}

extern "C" void kernel_launch(void* const* d_in, const int* in_sizes, int n_in,
                              void* d_out, int out_size, void* d_ws, size_t ws_size,
                              hipStream_t stream) {
    const float* A = (const float*)d_in[0];   // mh_attn_out [128][128][128]
    const float* K = (const float*)d_in[1];   // single_head_key [128][128][4096]
    const float* M = (const float*)d_in[2];   // mask [128][128][4096]
    float* O = (float*)d_out;                 // probs [128][128][4096]
    float* ws = (float*)d_ws;                 // 128*128*4 floats = 256 KB

    score_kernel<<<dim3(2048), dim3(512), 0, stream>>>(A, K, M, O, ws);
    scale_kernel<<<dim3(2048), dim3(256), 0, stream>>>(O, ws);
}

// Round 13
// 287.333 us; speedup vs baseline: 1.2692x; 1.2281x over previous
//
#include <hip/hip_runtime.h>
#include <math.h>

// Problem: B=128, P=128, D=128, N=4096, fp32 in/out.
// probs = softmax(10*tanh((A@K)/sqrt(128)) + mask) over n.
//
// R13: LDS-staged fp16x3 MFMA GEMM.
//  K1: per block: C-tile 128p x 128n. K tile loaded ONCE coalesced (f4),
//      split hi/lo ONCE into LDS [n][d] fp16; all 8 waves reuse it.
//      e = exp(10*tanh(score/sqrt(128)) + mask) -> O; row partials -> ws.
//      (max-free softmax valid: |10*tanh| <= 10 -> e <= 2.3e4, sum <= 9e7)
//  K2: O *= 1/rowsum (32 partials per row).
constexpr int BB = 128;
constexpr int PP = 128;
constexpr int DD = 128;
constexpr int NN = 4096;
constexpr float kC = 10.0f;
constexpr float k2InvSqrtD = 0.1767766952966369f;   // 2/sqrt(128)

constexpr int NTHR = 512;
constexpr int LSTR = 132;            // LDS row stride in fp16 (8B-aligned, pad 4)

typedef float f32x4 __attribute__((ext_vector_type(4)));
typedef _Float16 f16x4 __attribute__((ext_vector_type(4)));
typedef _Float16 f16x8 __attribute__((ext_vector_type(8)));

__device__ __forceinline__ void st_nt_f4(float* p, float4 s) {
    f32x4 v = {s.x, s.y, s.z, s.w};
    __builtin_nontemporal_store(v, (f32x4*)p);
}

// z = 10*tanh(s/sqrt(128)) + m, via tanh(x) = 1 - 2/(e^{2x}+1)
__device__ __forceinline__ float clip1(float s, float m) {
    const float e2 = __expf(s * k2InvSqrtD);
    const float r = __builtin_amdgcn_rcpf(e2 + 1.0f);
    return fmaf(-2.0f * kC, r, kC) + m;
}

// ===================== Kernel 1: staged GEMM + clip + exp =====================
// Grid: 4096 = 128 b x 32 n-tiles. 512 thr = 8 waves; wave w owns rows
// w*16..w*16+15, all 128 cols (8 MFMA tiles). fp16x3: score = hh + hl + lh
// (k-packing k = kb*32 + 4g + (j&3) + 16*(j>>2) applied identically to A and B
// -> any k-permutation cancels). C/D layout (HW-verified): col = lane&15,
// row = 4*(lane>>4) + reg.
__global__ __launch_bounds__(NTHR, 2)
void score_kernel(const float* __restrict__ A,   // [B][P][D]
                  const float* __restrict__ K,   // [B][D][N]
                  const float* __restrict__ M,   // [B][P][N]
                  float* __restrict__ O,         // [B][P][N] <- exp(z)
                  float* __restrict__ ws) {      // [B*P][32] partial row sums
    __shared__ _Float16 Khi[128 * LSTR];         // [n][d] 33 KB
    __shared__ _Float16 Klo[128 * LSTR];         // [n][d] 33 KB

    const int l = blockIdx.x;
    const int b = l >> 5;                  // blocks sharing b are consecutive
    const int ntb = l & 31;
    const int n_base = ntb * 128;

    const int tid = (int)threadIdx.x;
    const int lane = tid & 63;
    const int wid = tid >> 6;
    const int col = lane & 15;             // A row-in-frag / B col / C col
    const int g = lane >> 4;               // k-group / C row group
    const int kbase = 4 * g;

    // ---- Stage K tile [128 d][128 n] -> split fp16 LDS [n][d] (once/block) ----
    const float* Kg = K + (size_t)b * DD * NN + n_base;
    #pragma unroll
    for (int i = 0; i < 8; ++i) {
        const int f = tid + i * NTHR;      // [0,4096)
        const int d = f >> 5;
        const int n4 = (f & 31) << 2;
        const float4 v = *(const float4*)(Kg + (size_t)d * NN + n4);
        const float xs[4] = {v.x, v.y, v.z, v.w};
        #pragma unroll
        for (int e = 0; e < 4; ++e) {
            const float x = xs[e];
            const _Float16 h = (_Float16)x;
            Khi[(n4 + e) * LSTR + d] = h;
            Klo[(n4 + e) * LSTR + d] = (_Float16)(x - (float)h);
        }
    }

    // ---- A fragments (regs, whole kernel): 16 rows x 128 d per wave ----
    const float* Arow = A + (size_t)(b * PP + wid * 16 + col) * DD;
    f16x8 ah[4], al[4];
    #pragma unroll
    for (int kb = 0; kb < 4; ++kb) {
        #pragma unroll
        for (int j = 0; j < 8; ++j) {
            const int d = kb * 32 + kbase + (j & 3) + 16 * (j >> 2);
            const float x = Arow[d];
            const _Float16 h = (_Float16)x;
            ah[kb][j] = h;
            al[kb][j] = (_Float16)(x - (float)h);
        }
    }
    __syncthreads();

    // ---- Main loop over 8 n-subtiles ----
    // C rows for this lane: wid*16 + kbase + j, j=0..3; col: n_base + nt*16 + col
    const size_t mrow0 = (size_t)(b * PP + wid * 16 + kbase) * NN + n_base + col;

    float rsum[4] = {0.f, 0.f, 0.f, 0.f};
    float mv[4];
    #pragma unroll
    for (int j = 0; j < 4; ++j) mv[j] = M[mrow0 + (size_t)j * NN];

    #pragma unroll 2
    for (int nt = 0; nt < 8; ++nt) {
        // prefetch next tile's mask early (HBM latency under MFMAs)
        float mvn[4];
        if (nt < 7) {
            #pragma unroll
            for (int j = 0; j < 4; ++j)
                mvn[j] = M[mrow0 + (size_t)j * NN + (nt + 1) * 16];
        }

        const int nrow = (nt * 16 + col) * LSTR;
        f32x4 acc = {0.f, 0.f, 0.f, 0.f};
        #pragma unroll
        for (int kb = 0; kb < 4; ++kb) {
            const int d0 = kb * 32 + kbase;
            const f16x4 h0 = *(const f16x4*)&Khi[nrow + d0];
            const f16x4 h1 = *(const f16x4*)&Khi[nrow + d0 + 16];
            const f16x4 l0 = *(const f16x4*)&Klo[nrow + d0];
            const f16x4 l1 = *(const f16x4*)&Klo[nrow + d0 + 16];
            const f16x8 bh = __builtin_shufflevector(h0, h1, 0, 1, 2, 3, 4, 5, 6, 7);
            const f16x8 bl = __builtin_shufflevector(l0, l1, 0, 1, 2, 3, 4, 5, 6, 7);
            acc = __builtin_amdgcn_mfma_f32_16x16x32_f16(ah[kb], bh, acc, 0, 0, 0);
            acc = __builtin_amdgcn_mfma_f32_16x16x32_f16(ah[kb], bl, acc, 0, 0, 0);
            acc = __builtin_amdgcn_mfma_f32_16x16x32_f16(al[kb], bh, acc, 0, 0, 0);
        }

        // epilogue: e = exp(clip + mask); store; row partials
        #pragma unroll
        for (int j = 0; j < 4; ++j) {
            const size_t off = mrow0 + (size_t)j * NN + nt * 16;
            const float e = __expf(clip1(acc[j], mv[j]));
            O[off] = e;                    // cached: K2 re-reads via L2/L3
            rsum[j] += e;
        }
        #pragma unroll
        for (int j = 0; j < 4; ++j) mv[j] = mvn[j];
    }

    // ---- reduce row partials across the 16 cols of each group -> ws ----
    #pragma unroll
    for (int j = 0; j < 4; ++j) {
        float s = rsum[j];
        s += __shfl_xor(s, 1);
        s += __shfl_xor(s, 2);
        s += __shfl_xor(s, 4);
        s += __shfl_xor(s, 8);
        rsum[j] = s;
    }
    if (col == 0) {
        #pragma unroll
        for (int j = 0; j < 4; ++j)
            ws[(size_t)(b * PP + wid * 16 + kbase + j) * 32 + ntb] = rsum[j];
    }
}

// ========================= Kernel 2: scale by 1/rowsum ========================
// Pure streaming: 2048 blocks x 256 thr; 32 threads/row, 32 f4/thread.
__global__ __launch_bounds__(256, 4)
void scale_kernel(float* __restrict__ O, const float* __restrict__ ws) {
    const int gtid = blockIdx.x * 256 + (int)threadIdx.x;
    const int row = gtid >> 5;
    const int seg = gtid & 31;

    const float* w = ws + (size_t)row * 32;
    float s = 0.f;
    #pragma unroll
    for (int i = 0; i < 8; ++i) {
        const float4 v = *(const float4*)(w + i * 4);
        s += (v.x + v.y) + (v.z + v.w);
    }
    const float inv = __builtin_amdgcn_rcpf(s);

    float4* R = (float4*)(O + (size_t)row * NN);
    #pragma unroll 8
    for (int i = 0; i < 32; ++i) {
        const int idx = i * 32 + seg;      // lanes consecutive -> coalesced
        float4 v = R[idx];
        v.x *= inv; v.y *= inv; v.z *= inv; v.w *= inv;
        st_nt_f4((float*)&R[idx], v);
    }
}

extern "C" void kernel_launch(void* const* d_in, const int* in_sizes, int n_in,
                              void* d_out, int out_size, void* d_ws, size_t ws_size,
                              hipStream_t stream) {
    const float* A = (const float*)d_in[0];   // mh_attn_out [128][128][128]
    const float* K = (const float*)d_in[1];   // single_head_key [128][128][4096]
    const float* M = (const float*)d_in[2];   // mask [128][128][4096]
    float* O = (float*)d_out;                 // probs [128][128][4096]
    float* ws = (float*)d_ws;                 // 16384 rows x 32 partials = 2 MB

    score_kernel<<<dim3(BB * 32), dim3(NTHR), 0, stream>>>(A, K, M, O, ws);
    scale_kernel<<<dim3(2048), dim3(256), 0, stream>>>(O, ws);
}

// Round 14
// 286.020 us; speedup vs baseline: 1.2750x; 1.0046x over previous
//
#include <hip/hip_runtime.h>
#include <math.h>

// Problem: B=128, P=128, D=128, N=4096, fp32 in/out.
// probs = softmax(10*tanh((A@K)/sqrt(128)) + mask) over n.
//
// R14: LDS frag-packed fp16x3 MFMA GEMM.
//  K1: per block: C-tile 128p x 128n. K tile loaded once (coalesced f4),
//      split hi/lo once into LDS in MFMA-fragment order; reads are single
//      ds_read_b128 per operand, slot-rotated for bank balance.
//      e = exp(10*tanh(score/sqrt(128)) + mask) -> O; row partials -> ws.
//      (max-free softmax: |10*tanh| <= 10 -> e <= 2.3e4, sum <= 9e7)
//  K2: O *= 1/rowsum (32 partials per row).
constexpr int BB = 128;
constexpr int PP = 128;
constexpr int DD = 128;
constexpr int NN = 4096;
constexpr float kC = 10.0f;
constexpr float k2InvSqrtD = 0.1767766952966369f;   // 2/sqrt(128)

constexpr int NTHR = 512;
constexpr int RS = 264;              // LDS row stride in fp16 (528 B; slot rot = row mod 8)

typedef float f32x4 __attribute__((ext_vector_type(4)));
typedef _Float16 f16x8 __attribute__((ext_vector_type(8)));

__device__ __forceinline__ void st_nt_f4(float* p, float4 s) {
    f32x4 v = {s.x, s.y, s.z, s.w};
    __builtin_nontemporal_store(v, (f32x4*)p);
}

// z = 10*tanh(s/sqrt(128)) + m, via tanh(x) = 1 - 2/(e^{2x}+1)
__device__ __forceinline__ float clip1(float s, float m) {
    const float e2 = __expf(s * k2InvSqrtD);
    const float r = __builtin_amdgcn_rcpf(e2 + 1.0f);
    return fmaf(-2.0f * kC, r, kC) + m;
}

// ===================== Kernel 1: staged GEMM + clip + exp =====================
// Grid: 4096 = 128 b x 32 n-tiles. 512 thr = 8 waves; wave w owns rows w*16..+15,
// all 128 cols. fp16x3: score = hh + hl + lh (k-packing k = kb*32 + 4g +
// (j&3) + 16*(j>>2), identical on A and B -> any k-permutation cancels).
// C/D layout (HW-verified): col = lane&15, row = 4*(lane>>4) + reg.
//
// LDS layout: row n holds 32 frags x 8 fp16 (16B): frag(kb,g,hl) at granule
// gran = kb*8 + ((2g + hl + rot(n)) & 7), rot(n) = (n>>2)&3. 16B-slot index
// = (n + gran) mod 8 -> reads bijective over col (conflict-free); writes ~4-way.
__global__ __launch_bounds__(NTHR, 2)
void score_kernel(const float* __restrict__ A,   // [B][P][D]
                  const float* __restrict__ K,   // [B][D][N]
                  const float* __restrict__ M,   // [B][P][N]
                  float* __restrict__ O,         // [B][P][N] <- exp(z)
                  float* __restrict__ ws) {      // [B*P][32] partial row sums
    __shared__ _Float16 Kf[128 * RS];            // 66 KB

    const int l = blockIdx.x;
    const int b = l >> 5;
    const int ntb = l & 31;
    const int n_base = ntb * 128;

    const int tid = (int)threadIdx.x;
    const int lane = tid & 63;
    const int wid = tid >> 6;
    const int col = lane & 15;             // A row-in-frag / B col / C col
    const int g = lane >> 4;               // k-group / C row group
    const int kbase = 4 * g;

    // ---- Stage K tile [128 d][128 n] -> frag-packed hi/lo LDS (once/block) ----
    const float* Kg = K + (size_t)b * DD * NN + n_base;
    {
        const int d0 = tid >> 5;           // d = d0 + 16*i
        const int tn = (tid & 31) * 4;     // 4 consecutive n
        const int rotw = tid & 3;          // (n>>2)&3 for n = tn+e (e<4)
        #pragma unroll
        for (int i = 0; i < 8; ++i) {
            const int d = d0 + 16 * i;
            const int kb = d >> 5;
            const int dk = d & 31;
            const int gw = (dk & 15) >> 2;
            const int j = (dk & 3) + 4 * (dk >> 4);
            const int granh = kb * 8 + ((2 * gw + rotw) & 7);
            const int granl = kb * 8 + ((2 * gw + 1 + rotw) & 7);
            const float4 v = *(const float4*)(Kg + (size_t)d * NN + tn);
            const float xs[4] = {v.x, v.y, v.z, v.w};
            #pragma unroll
            for (int e = 0; e < 4; ++e) {
                const float x = xs[e];
                const _Float16 h = (_Float16)x;
                const int base = (tn + e) * RS;
                Kf[base + granh * 8 + j] = h;
                Kf[base + granl * 8 + j] = (_Float16)(x - (float)h);
            }
        }
    }

    // ---- A fragments (regs, whole kernel): 16 rows x 128 d per wave ----
    const float* Arow = A + (size_t)(b * PP + wid * 16 + col) * DD;
    f16x8 ah[4], al[4];
    #pragma unroll
    for (int kb = 0; kb < 4; ++kb) {
        #pragma unroll
        for (int j = 0; j < 8; ++j) {
            const int d = kb * 32 + kbase + (j & 3) + 16 * (j >> 2);
            const float x = Arow[d];
            const _Float16 h = (_Float16)x;
            ah[kb][j] = h;
            al[kb][j] = (_Float16)(x - (float)h);
        }
    }

    // per-thread constant read offsets (rot depends only on (col>>2)&3)
    int offH[4], offL[4];
    {
        const int rotr = (col >> 2) & 3;
        #pragma unroll
        for (int kb = 0; kb < 4; ++kb) {
            offH[kb] = kb * 64 + ((2 * g + rotr) & 7) * 8;
            offL[kb] = kb * 64 + ((2 * g + 1 + rotr) & 7) * 8;
        }
    }
    __syncthreads();

    // ---- Main loop over 8 n-subtiles ----
    const size_t mrow0 = (size_t)(b * PP + wid * 16 + kbase) * NN + n_base + col;

    float rsum[4] = {0.f, 0.f, 0.f, 0.f};
    float mv[4];
    #pragma unroll
    for (int j = 0; j < 4; ++j) mv[j] = M[mrow0 + (size_t)j * NN];

    #pragma unroll 2
    for (int nt = 0; nt < 8; ++nt) {
        // prefetch next tile's mask early (HBM latency under MFMAs)
        float mvn[4];
        if (nt < 7) {
            #pragma unroll
            for (int j = 0; j < 4; ++j)
                mvn[j] = M[mrow0 + (size_t)j * NN + (nt + 1) * 16];
        }

        const _Float16* Krow = &Kf[(nt * 16 + col) * RS];
        f32x4 acc = {0.f, 0.f, 0.f, 0.f};
        #pragma unroll
        for (int kb = 0; kb < 4; ++kb) {
            const f16x8 bh = *(const f16x8*)(Krow + offH[kb]);
            const f16x8 bl = *(const f16x8*)(Krow + offL[kb]);
            acc = __builtin_amdgcn_mfma_f32_16x16x32_f16(ah[kb], bh, acc, 0, 0, 0);
            acc = __builtin_amdgcn_mfma_f32_16x16x32_f16(ah[kb], bl, acc, 0, 0, 0);
            acc = __builtin_amdgcn_mfma_f32_16x16x32_f16(al[kb], bh, acc, 0, 0, 0);
        }

        // epilogue: e = exp(clip + mask); store; row partials
        #pragma unroll
        for (int j = 0; j < 4; ++j) {
            const size_t off = mrow0 + (size_t)j * NN + nt * 16;
            const float e = __expf(clip1(acc[j], mv[j]));
            O[off] = e;                    // cached: K2 re-reads via L2/L3
            rsum[j] += e;
        }
        #pragma unroll
        for (int j = 0; j < 4; ++j) mv[j] = mvn[j];
    }

    // ---- reduce row partials across the 16 cols of each group -> ws ----
    #pragma unroll
    for (int j = 0; j < 4; ++j) {
        float s = rsum[j];
        s += __shfl_xor(s, 1);
        s += __shfl_xor(s, 2);
        s += __shfl_xor(s, 4);
        s += __shfl_xor(s, 8);
        rsum[j] = s;
    }
    if (col == 0) {
        #pragma unroll
        for (int j = 0; j < 4; ++j)
            ws[(size_t)(b * PP + wid * 16 + kbase + j) * 32 + ntb] = rsum[j];
    }
}

// ========================= Kernel 2: scale by 1/rowsum ========================
// Pure streaming: 2048 blocks x 256 thr; 32 threads/row, 32 f4/thread.
__global__ __launch_bounds__(256, 4)
void scale_kernel(float* __restrict__ O, const float* __restrict__ ws) {
    const int gtid = blockIdx.x * 256 + (int)threadIdx.x;
    const int row = gtid >> 5;
    const int seg = gtid & 31;

    const float* w = ws + (size_t)row * 32;
    float s = 0.f;
    #pragma unroll
    for (int i = 0; i < 8; ++i) {
        const float4 v = *(const float4*)(w + i * 4);
        s += (v.x + v.y) + (v.z + v.w);
    }
    const float inv = __builtin_amdgcn_rcpf(s);

    float4* R = (float4*)(O + (size_t)row * NN);
    #pragma unroll 8
    for (int i = 0; i < 32; ++i) {
        const int idx = i * 32 + seg;      // lanes consecutive -> coalesced
        float4 v = R[idx];
        v.x *= inv; v.y *= inv; v.z *= inv; v.w *= inv;
        st_nt_f4((float*)&R[idx], v);
    }
}

extern "C" void kernel_launch(void* const* d_in, const int* in_sizes, int n_in,
                              void* d_out, int out_size, void* d_ws, size_t ws_size,
                              hipStream_t stream) {
    const float* A = (const float*)d_in[0];   // mh_attn_out [128][128][128]
    const float* K = (const float*)d_in[1];   // single_head_key [128][128][4096]
    const float* M = (const float*)d_in[2];   // mask [128][128][4096]
    float* O = (float*)d_out;                 // probs [128][128][4096]
    float* ws = (float*)d_ws;                 // 16384 rows x 32 partials = 2 MB

    score_kernel<<<dim3(BB * 32), dim3(NTHR), 0, stream>>>(A, K, M, O, ws);
    scale_kernel<<<dim3(2048), dim3(256), 0, stream>>>(O, ws);
}